// Round 6
// baseline (491.608 us; speedup 1.0000x reference)
//
#include <hip/hip_runtime.h>
#include <hip/hip_bf16.h>

typedef __bf16 bf16_t;
typedef short  s4    __attribute__((ext_vector_type(4)));
typedef short  s8    __attribute__((ext_vector_type(8)));
typedef float  f32x4 __attribute__((ext_vector_type(4)));

#define TPW   8                      // tiles per wave
#define WAVES 4
#define ROWS_PER_BLOCK (WAVES * TPW * 16)   // 512 -> grid = 2048 = 8 blocks/CU queued

__device__ __forceinline__ short bfs(float f) {
    return __builtin_bit_cast(short, (bf16_t)f);
}
__device__ __forceinline__ s4 pack4(f32x4 a) {
    s4 r; r[0]=bfs(a[0]); r[1]=bfs(a[1]); r[2]=bfs(a[2]); r[3]=bfs(a[3]); return r;
}
__device__ __forceinline__ s4 relu_pack4(f32x4 a) {
    s4 r;
    r[0]=bfs(fmaxf(a[0],0.f)); r[1]=bfs(fmaxf(a[1],0.f));
    r[2]=bfs(fmaxf(a[2],0.f)); r[3]=bfs(fmaxf(a[3],0.f));
    return r;
}
__device__ __forceinline__ s8 cat(s4 a, s4 b) {
    return __builtin_shufflevector(a, b, 0, 1, 2, 3, 4, 5, 6, 7);
}
// Native gfx950 shape: D = A*B + C, 16x16x32 bf16. k-map agnostic fragment
// construction (A and B gathered with the same per-(lane-group, elem) k order);
// C/D layout: col=lane&15, row=4*(lane>>4)+reg => a layer's D regs are exactly
// the next layer's B regs (after relu+pack+cat).
#define MFMA32(a,b,c) __builtin_amdgcn_mfma_f32_16x16x32_bf16(a, b, c, 0, 0, 0)

// Weight A-fragment gather for LDS staging. Frag index map:
//  0..3  L1 (t)        [32,64]
//  4..5  L2 (j)        [64,16]
//  6..9  L3 (t)        [32,64]
// 10..17 L4 (2*tt+j)   [64,64]
// 18..19 L5 (j)        [64,3] zero-padded
__device__ __forceinline__ s8 gather_frag(int f, int q, int n,
    const float* W1, const float* W2, const float* W3,
    const float* W4, const float* W5)
{
    s8 r;
    if (f < 4) {
        const int t = f;
        #pragma unroll
        for (int h = 0; h < 2; ++h)
            #pragma unroll
            for (int i = 0; i < 4; ++i)
                r[4*h+i] = bfs(W1[(16*h + 4*q + i) * 64 + 16*t + n]);
    } else if (f < 6) {
        const int j = f - 4;
        #pragma unroll
        for (int h = 0; h < 2; ++h)
            #pragma unroll
            for (int i = 0; i < 4; ++i)
                r[4*h+i] = bfs(W2[(16*(2*j+h) + 4*q + i) * 16 + n]);
    } else if (f < 10) {
        const int t = f - 6;
        #pragma unroll
        for (int h = 0; h < 2; ++h)
            #pragma unroll
            for (int i = 0; i < 4; ++i)
                r[4*h+i] = bfs(W3[(16*h + 4*q + i) * 64 + 16*t + n]);
    } else if (f < 18) {
        const int tt = (f - 10) >> 1, j = (f - 10) & 1;
        #pragma unroll
        for (int h = 0; h < 2; ++h)
            #pragma unroll
            for (int i = 0; i < 4; ++i)
                r[4*h+i] = bfs(W4[(16*(2*j+h) + 4*q + i) * 64 + 16*tt + n]);
    } else {
        const int j = f - 18;
        #pragma unroll
        for (int h = 0; h < 2; ++h)
            #pragma unroll
            for (int i = 0; i < 4; ++i)
                r[4*h+i] = (n < 3) ? bfs(W5[(16*(2*j+h) + 4*q + i) * 3 + n])
                                   : (short)0;
    }
    return r;
}

// __launch_bounds__(256, 6): VGPR cap ~84 -> 6 waves/SIMD resident (vs 4 in all
// prior rounds). Working set after LDS-ifying weights+biases is ~65-80 VGPR, so
// the cap should be met WITHOUT spills (round-1 disaster was cap 64 vs need 136).
// Tripwire: FETCH_SIZE >> 72 MB means scratch traffic -> revert the cap.
__global__ __launch_bounds__(256, 6) void nerf_fused(
    const float* __restrict__ pos, const float* __restrict__ dir,
    const float* __restrict__ W1, const float* __restrict__ b1,
    const float* __restrict__ W2, const float* __restrict__ b2,
    const float* __restrict__ W3, const float* __restrict__ b3,
    const float* __restrict__ W4, const float* __restrict__ b4,
    const float* __restrict__ W5, const float* __restrict__ b5,
    float* __restrict__ outD, float* __restrict__ outC)
{
    // All weight A-fragments (lane-contiguous 16B rows => conflict-free b128)
    // + b1/b3/b4 bias vectors (linear layout; per-q f32x4 reads broadcast).
    __shared__ s8    wlds[20 * 64];
    __shared__ float blds[3 * 64];

    const int tid  = threadIdx.x;
    const int w    = tid >> 6;
    const int lane = tid & 63;
    const int q    = lane >> 4;    // lane-group 0..3
    const int n    = lane & 15;    // A row / B col / sample-within-tile

    // ---------- stage weights: wave w gathers fragments 5w..5w+4 ----------
    #pragma unroll
    for (int f5 = 0; f5 < 5; ++f5) {
        const int f = w * 5 + f5;
        wlds[f * 64 + lane] = gather_frag(f, q, n, W1, W2, W3, W4, W5);
    }
    if (tid < 64) {
        blds[tid]       = b1[tid];
        blds[64 + tid]  = b3[tid];
        blds[128 + tid] = b4[tid];
    }
    __syncthreads();   // LDS read-only below

    // small biases kept in regs
    f32x4 bi2, bi5;
    #pragma unroll
    for (int r = 0; r < 4; ++r) {
        bi2[r] = b2[4*q + r];
        bi5[r] = (q == 0 && r < 3) ? b5[r] : 0.f;
    }

    const int waveRow0 = blockIdx.x * ROWS_PER_BLOCK + w * (TPW * 16);

    // per-lane streaming pointers (constant per-tile strides)
    const float* pp = pos  + (size_t)(waveRow0 + n) * 32 + 4*q;
    const float* dp = dir  + (size_t)(waveRow0 + n) * 3;
    float*       pD = outD + (size_t)(waveRow0 + n) * 16 + 4*q;
    float*       pC = outC + (size_t)(waveRow0 + n) * 3;   // only used by q==0 lanes

    for (int t = 0; t < TPW; ++t) {
        // just-in-time input loads (L3-resident; latency hidden by 6 waves/SIMD)
        f32x4 pa = *(const f32x4*)pp;
        f32x4 pb = *(const f32x4*)(pp + 16);
        float dx = dp[0], dy = dp[1], dz = dp[2];

        s8 xb = cat(pack4(pa), pack4(pb));

        // ---- L1: H^T = W1^T · X^T  (4 h-tiles, K=32) ----
        s4 hf[4];
        #pragma unroll
        for (int tt = 0; tt < 4; ++tt) {
            f32x4 bi = *(const f32x4*)(blds + 16*tt + 4*q);
            f32x4 h  = MFMA32(wlds[tt * 64 + lane], xb, bi);
            hf[tt] = relu_pack4(h);          // D regs == next-layer B regs
        }

        // ---- L2: density (K=64 -> 2 chained MFMAs, no relu) ----
        f32x4 d2 = MFMA32(wlds[4 * 64 + lane], cat(hf[0], hf[1]), bi2);
        d2 = MFMA32(wlds[5 * 64 + lane], cat(hf[2], hf[3]), d2);

        // direct coalesced density store (lane(q,n): channels 4q..4q+3 of sample n)
        *(f32x4*)pD = d2;

        // ---- SH encoding (exec-masked by q; cost = sum of branches) ----
        f32x4 shv;
        {
            const float xx = dx*dx, yy = dy*dy, zz = dz*dz;
            if (q == 0) {
                shv[0] = 0.28209479177387814f;
                shv[1] = 0.4886025119029199f * dy;
                shv[2] = 0.4886025119029199f * dz;
                shv[3] = 0.4886025119029199f * dx;
            } else if (q == 1) {
                shv[0] = 1.0925484305920792f * dx * dy;
                shv[1] = 1.0925484305920792f * dy * dz;
                shv[2] = 0.9461746957575601f * zz - 0.31539156525252f;
                shv[3] = 1.0925484305920792f * dx * dz;
            } else if (q == 2) {
                shv[0] = 0.5462742152960396f * (xx - yy);
                shv[1] = 0.5900435899266435f * dy * (3.f*xx - yy);
                shv[2] = 2.890611442640554f * dx * dy * dz;
                shv[3] = 0.4570457994644658f * dy * (5.f*zz - 1.f);
            } else {
                shv[0] = 0.3731763325901154f * dz * (5.f*zz - 3.f);
                shv[1] = 0.4570457994644658f * dx * (5.f*zz - 1.f);
                shv[2] = 1.445305721320277f  * dz * (xx - yy);
                shv[3] = 0.5900435899266435f * dx * (xx - 3.f*yy);
            }
        }
        s8 cf = cat(pack4(d2), pack4(shv));

        // ---- L3: relu(W3^T · concat^T)  (4 h-tiles, K=32) ----
        s4 gf[4];
        #pragma unroll
        for (int tt = 0; tt < 4; ++tt) {
            f32x4 bi = *(const f32x4*)(blds + 64 + 16*tt + 4*q);
            f32x4 g  = MFMA32(wlds[(6 + tt) * 64 + lane], cf, bi);
            gf[tt] = relu_pack4(g);
        }

        // ---- L4: relu(W4^T · H3^T)  (K=64 -> 2 chained MFMAs per tt) ----
        s8 gl = cat(gf[0], gf[1]), gh = cat(gf[2], gf[3]);
        s4 ef[4];
        #pragma unroll
        for (int tt = 0; tt < 4; ++tt) {
            f32x4 bi = *(const f32x4*)(blds + 128 + 16*tt + 4*q);
            f32x4 e  = MFMA32(wlds[(10 + 2*tt) * 64 + lane], gl, bi);
            e = MFMA32(wlds[(11 + 2*tt) * 64 + lane], gh, e);
            ef[tt] = relu_pack4(e);
        }

        // ---- L5: color (K=64 -> 2 chained MFMAs) + sigmoid ----
        f32x4 c5 = MFMA32(wlds[18 * 64 + lane], cat(ef[0], ef[1]), bi5);
        c5 = MFMA32(wlds[19 * 64 + lane], cat(ef[2], ef[3]), c5);

        f32x4 cv;
        cv[0] = 1.f / (1.f + __expf(-c5[0]));
        cv[1] = 1.f / (1.f + __expf(-c5[1]));
        cv[2] = 1.f / (1.f + __expf(-c5[2]));
        if (q == 0) {
            pC[0] = cv[0];
            pC[1] = cv[1];
            pC[2] = cv[2];
        }

        pp += 16 * 32; dp += 16 * 3; pD += 16 * 16; pC += 16 * 3;
    }
}

extern "C" void kernel_launch(void* const* d_in, const int* in_sizes, int n_in,
                              void* d_out, int out_size, void* d_ws, size_t ws_size,
                              hipStream_t stream) {
    const float* pos = (const float*)d_in[0];
    const float* dir = (const float*)d_in[1];
    const float* W1  = (const float*)d_in[2];
    const float* b1  = (const float*)d_in[3];
    const float* W2  = (const float*)d_in[4];
    const float* b2  = (const float*)d_in[5];
    const float* W3  = (const float*)d_in[6];
    const float* b3  = (const float*)d_in[7];
    const float* W4  = (const float*)d_in[8];
    const float* b4  = (const float*)d_in[9];
    const float* W5  = (const float*)d_in[10];
    const float* b5  = (const float*)d_in[11];

    const int N = in_sizes[0] / 32;           // 1<<20
    float* outD = (float*)d_out;              // [N,16]
    float* outC = outD + (size_t)N * 16;      // [N,3]

    const int grid = N / ROWS_PER_BLOCK;      // 2048
    nerf_fused<<<grid, WAVES * 64, 0, stream>>>(pos, dir, W1, b1, W2, b2, W3, b3,
                                                W4, b4, W5, b5, outD, outC);
}

// Round 7
// 272.602 us; speedup vs baseline: 1.8034x; 1.8034x over previous
//
#include <hip/hip_runtime.h>
#include <hip/hip_bf16.h>

typedef __bf16 bf16_t;
typedef short  s4    __attribute__((ext_vector_type(4)));
typedef short  s8    __attribute__((ext_vector_type(8)));
typedef float  f32x4 __attribute__((ext_vector_type(4)));

#define TPW   8                      // tiles per wave
#define WAVES 4
#define ROWS_PER_BLOCK (WAVES * TPW * 16)   // 512 -> grid = 2048 = 8 blocks/CU queued

__device__ __forceinline__ short bfs(float f) {
    return __builtin_bit_cast(short, (bf16_t)f);
}
__device__ __forceinline__ s4 pack4(f32x4 a) {
    s4 r; r[0]=bfs(a[0]); r[1]=bfs(a[1]); r[2]=bfs(a[2]); r[3]=bfs(a[3]); return r;
}
__device__ __forceinline__ s4 relu_pack4(f32x4 a) {
    s4 r;
    r[0]=bfs(fmaxf(a[0],0.f)); r[1]=bfs(fmaxf(a[1],0.f));
    r[2]=bfs(fmaxf(a[2],0.f)); r[3]=bfs(fmaxf(a[3],0.f));
    return r;
}
__device__ __forceinline__ s8 cat(s4 a, s4 b) {
    return __builtin_shufflevector(a, b, 0, 1, 2, 3, 4, 5, 6, 7);
}
// Native gfx950 shape: D = A*B + C, 16x16x32 bf16. k-map agnostic fragment
// construction (A and B gathered with the same per-(lane-group, elem) k order);
// C/D layout: col=lane&15, row=4*(lane>>4)+reg => a layer's D regs are exactly
// the next layer's B regs (after relu+pack+cat).
#define MFMA32(a,b,c) __builtin_amdgcn_mfma_f32_16x16x32_bf16(a, b, c, 0, 0, 0)

// Weight A-fragment gather for LDS staging. Frag index map:
//  0..3  L1 (t)        [32,64]
//  4..5  L2 (j)        [64,16]
//  6..9  L3 (t)        [32,64]
// 10..17 L4 (2*tt+j)   [64,64]
// 18..19 L5 (j)        [64,3] zero-padded
__device__ __forceinline__ s8 gather_frag(int f, int q, int n,
    const float* W1, const float* W2, const float* W3,
    const float* W4, const float* W5)
{
    s8 r;
    if (f < 4) {
        const int t = f;
        #pragma unroll
        for (int h = 0; h < 2; ++h)
            #pragma unroll
            for (int i = 0; i < 4; ++i)
                r[4*h+i] = bfs(W1[(16*h + 4*q + i) * 64 + 16*t + n]);
    } else if (f < 6) {
        const int j = f - 4;
        #pragma unroll
        for (int h = 0; h < 2; ++h)
            #pragma unroll
            for (int i = 0; i < 4; ++i)
                r[4*h+i] = bfs(W2[(16*(2*j+h) + 4*q + i) * 16 + n]);
    } else if (f < 10) {
        const int t = f - 6;
        #pragma unroll
        for (int h = 0; h < 2; ++h)
            #pragma unroll
            for (int i = 0; i < 4; ++i)
                r[4*h+i] = bfs(W3[(16*h + 4*q + i) * 64 + 16*t + n]);
    } else if (f < 18) {
        const int tt = (f - 10) >> 1, j = (f - 10) & 1;
        #pragma unroll
        for (int h = 0; h < 2; ++h)
            #pragma unroll
            for (int i = 0; i < 4; ++i)
                r[4*h+i] = bfs(W4[(16*(2*j+h) + 4*q + i) * 64 + 16*tt + n]);
    } else {
        const int j = f - 18;
        #pragma unroll
        for (int h = 0; h < 2; ++h)
            #pragma unroll
            for (int i = 0; i < 4; ++i)
                r[4*h+i] = (n < 3) ? bfs(W5[(16*(2*j+h) + 4*q + i) * 3 + n])
                                   : (short)0;
    }
    return r;
}

// Plain __launch_bounds__(256): NO min-waves bound. Measured history:
//  - (256,4) cap 128 vs need 136 -> spill catastrophe (round 1)
//  - (256,6) cap 85             -> allocator collapsed to 40 VGPR, 900 MB of
//    scratch traffic, 4x regression (round 6)
// The LDS-resident-weights structure removes ~100 VGPRs of persistent state;
// let the allocator pick its natural count. If it lands <=102, we get 5
// waves/SIMD for free; if <=85, 6 waves/SIMD.
__global__ __launch_bounds__(256) void nerf_fused(
    const float* __restrict__ pos, const float* __restrict__ dir,
    const float* __restrict__ W1, const float* __restrict__ b1,
    const float* __restrict__ W2, const float* __restrict__ b2,
    const float* __restrict__ W3, const float* __restrict__ b3,
    const float* __restrict__ W4, const float* __restrict__ b4,
    const float* __restrict__ W5, const float* __restrict__ b5,
    float* __restrict__ outD, float* __restrict__ outC)
{
    // All weight A-fragments (lane-contiguous 16B rows => conflict-free b128)
    // + b1/b3/b4 bias vectors (linear layout; per-q f32x4 reads broadcast).
    __shared__ s8    wlds[20 * 64];
    __shared__ float blds[3 * 64];

    const int tid  = threadIdx.x;
    const int w    = tid >> 6;
    const int lane = tid & 63;
    const int q    = lane >> 4;    // lane-group 0..3
    const int n    = lane & 15;    // A row / B col / sample-within-tile

    // ---------- stage weights: wave w gathers fragments 5w..5w+4 ----------
    #pragma unroll
    for (int f5 = 0; f5 < 5; ++f5) {
        const int f = w * 5 + f5;
        wlds[f * 64 + lane] = gather_frag(f, q, n, W1, W2, W3, W4, W5);
    }
    if (tid < 64) {
        blds[tid]       = b1[tid];
        blds[64 + tid]  = b3[tid];
        blds[128 + tid] = b4[tid];
    }
    __syncthreads();   // LDS read-only below

    // small biases kept in regs
    f32x4 bi2, bi5;
    #pragma unroll
    for (int r = 0; r < 4; ++r) {
        bi2[r] = b2[4*q + r];
        bi5[r] = (q == 0 && r < 3) ? b5[r] : 0.f;
    }

    const int waveRow0 = blockIdx.x * ROWS_PER_BLOCK + w * (TPW * 16);

    // per-lane streaming pointers (constant per-tile strides)
    const float* pp = pos  + (size_t)(waveRow0 + n) * 32 + 4*q;
    const float* dp = dir  + (size_t)(waveRow0 + n) * 3;
    float*       pD = outD + (size_t)(waveRow0 + n) * 16 + 4*q;
    float*       pC = outC + (size_t)(waveRow0 + n) * 3;   // only used by q==0 lanes

    for (int t = 0; t < TPW; ++t) {
        // just-in-time input loads (L2/L3-resident; latency hidden by TLP)
        f32x4 pa = *(const f32x4*)pp;
        f32x4 pb = *(const f32x4*)(pp + 16);
        float dx = dp[0], dy = dp[1], dz = dp[2];

        s8 xb = cat(pack4(pa), pack4(pb));

        // ---- L1: H^T = W1^T · X^T  (4 h-tiles, K=32) ----
        s4 hf[4];
        #pragma unroll
        for (int tt = 0; tt < 4; ++tt) {
            f32x4 bi = *(const f32x4*)(blds + 16*tt + 4*q);
            f32x4 h  = MFMA32(wlds[tt * 64 + lane], xb, bi);
            hf[tt] = relu_pack4(h);          // D regs == next-layer B regs
        }

        // ---- L2: density (K=64 -> 2 chained MFMAs, no relu) ----
        f32x4 d2 = MFMA32(wlds[4 * 64 + lane], cat(hf[0], hf[1]), bi2);
        d2 = MFMA32(wlds[5 * 64 + lane], cat(hf[2], hf[3]), d2);

        // direct coalesced density store (lane(q,n): channels 4q..4q+3 of sample n)
        *(f32x4*)pD = d2;

        // ---- SH encoding (exec-masked by q; cost = sum of branches) ----
        f32x4 shv;
        {
            const float xx = dx*dx, yy = dy*dy, zz = dz*dz;
            if (q == 0) {
                shv[0] = 0.28209479177387814f;
                shv[1] = 0.4886025119029199f * dy;
                shv[2] = 0.4886025119029199f * dz;
                shv[3] = 0.4886025119029199f * dx;
            } else if (q == 1) {
                shv[0] = 1.0925484305920792f * dx * dy;
                shv[1] = 1.0925484305920792f * dy * dz;
                shv[2] = 0.9461746957575601f * zz - 0.31539156525252f;
                shv[3] = 1.0925484305920792f * dx * dz;
            } else if (q == 2) {
                shv[0] = 0.5462742152960396f * (xx - yy);
                shv[1] = 0.5900435899266435f * dy * (3.f*xx - yy);
                shv[2] = 2.890611442640554f * dx * dy * dz;
                shv[3] = 0.4570457994644658f * dy * (5.f*zz - 1.f);
            } else {
                shv[0] = 0.3731763325901154f * dz * (5.f*zz - 3.f);
                shv[1] = 0.4570457994644658f * dx * (5.f*zz - 1.f);
                shv[2] = 1.445305721320277f  * dz * (xx - yy);
                shv[3] = 0.5900435899266435f * dx * (xx - 3.f*yy);
            }
        }
        s8 cf = cat(pack4(d2), pack4(shv));

        // ---- L3: relu(W3^T · concat^T)  (4 h-tiles, K=32) ----
        s4 gf[4];
        #pragma unroll
        for (int tt = 0; tt < 4; ++tt) {
            f32x4 bi = *(const f32x4*)(blds + 64 + 16*tt + 4*q);
            f32x4 g  = MFMA32(wlds[(6 + tt) * 64 + lane], cf, bi);
            gf[tt] = relu_pack4(g);
        }

        // ---- L4: relu(W4^T · H3^T)  (K=64 -> 2 chained MFMAs per tt) ----
        s8 gl = cat(gf[0], gf[1]), gh = cat(gf[2], gf[3]);
        s4 ef[4];
        #pragma unroll
        for (int tt = 0; tt < 4; ++tt) {
            f32x4 bi = *(const f32x4*)(blds + 128 + 16*tt + 4*q);
            f32x4 e  = MFMA32(wlds[(10 + 2*tt) * 64 + lane], gl, bi);
            e = MFMA32(wlds[(11 + 2*tt) * 64 + lane], gh, e);
            ef[tt] = relu_pack4(e);
        }

        // ---- L5: color (K=64 -> 2 chained MFMAs) + sigmoid ----
        f32x4 c5 = MFMA32(wlds[18 * 64 + lane], cat(ef[0], ef[1]), bi5);
        c5 = MFMA32(wlds[19 * 64 + lane], cat(ef[2], ef[3]), c5);

        f32x4 cv;
        cv[0] = 1.f / (1.f + __expf(-c5[0]));
        cv[1] = 1.f / (1.f + __expf(-c5[1]));
        cv[2] = 1.f / (1.f + __expf(-c5[2]));
        if (q == 0) {
            pC[0] = cv[0];
            pC[1] = cv[1];
            pC[2] = cv[2];
        }

        pp += 16 * 32; dp += 16 * 3; pD += 16 * 16; pC += 16 * 3;
    }
}

extern "C" void kernel_launch(void* const* d_in, const int* in_sizes, int n_in,
                              void* d_out, int out_size, void* d_ws, size_t ws_size,
                              hipStream_t stream) {
    const float* pos = (const float*)d_in[0];
    const float* dir = (const float*)d_in[1];
    const float* W1  = (const float*)d_in[2];
    const float* b1  = (const float*)d_in[3];
    const float* W2  = (const float*)d_in[4];
    const float* b2  = (const float*)d_in[5];
    const float* W3  = (const float*)d_in[6];
    const float* b3  = (const float*)d_in[7];
    const float* W4  = (const float*)d_in[8];
    const float* b4  = (const float*)d_in[9];
    const float* W5  = (const float*)d_in[10];
    const float* b5  = (const float*)d_in[11];

    const int N = in_sizes[0] / 32;           // 1<<20
    float* outD = (float*)d_out;              // [N,16]
    float* outC = outD + (size_t)N * 16;      // [N,3]

    const int grid = N / ROWS_PER_BLOCK;      // 2048
    nerf_fused<<<grid, WAVES * 64, 0, stream>>>(pos, dir, W1, b1, W2, b2, W3, b3,
                                                W4, b4, W5, b5, outD, outC);
}

// Round 8
// 264.078 us; speedup vs baseline: 1.8616x; 1.0323x over previous
//
#include <hip/hip_runtime.h>
#include <hip/hip_bf16.h>

typedef __bf16 bf16_t;
typedef short  s4    __attribute__((ext_vector_type(4)));
typedef short  s8    __attribute__((ext_vector_type(8)));
typedef float  f32x4 __attribute__((ext_vector_type(4)));

#define TPW   8                      // tiles per wave
#define WAVES 4
#define ROWS_PER_BLOCK (WAVES * TPW * 16)   // 512 -> grid = 2048 = 8 blocks/CU queued

__device__ __forceinline__ short bfs(float f) {
    return __builtin_bit_cast(short, (bf16_t)f);
}
__device__ __forceinline__ s4 pack4(f32x4 a) {
    s4 r; r[0]=bfs(a[0]); r[1]=bfs(a[1]); r[2]=bfs(a[2]); r[3]=bfs(a[3]); return r;
}
__device__ __forceinline__ s4 relu_pack4(f32x4 a) {
    s4 r;
    r[0]=bfs(fmaxf(a[0],0.f)); r[1]=bfs(fmaxf(a[1],0.f));
    r[2]=bfs(fmaxf(a[2],0.f)); r[3]=bfs(fmaxf(a[3],0.f));
    return r;
}
__device__ __forceinline__ s8 cat(s4 a, s4 b) {
    return __builtin_shufflevector(a, b, 0, 1, 2, 3, 4, 5, 6, 7);
}
// Native gfx950 shape: D = A*B + C, 16x16x32 bf16. k-map agnostic fragment
// construction (A and B gathered with the same per-(lane-group, elem) k order);
// C/D layout: col=lane&15, row=4*(lane>>4)+reg => a layer's D regs are exactly
// the next layer's B regs (after relu+pack+cat).
#define MFMA32(a,b,c) __builtin_amdgcn_mfma_f32_16x16x32_bf16(a, b, c, 0, 0, 0)

// Register-budget design (learned rounds 1/6/7):
//  - NEVER use a min-waves __launch_bounds__ cap: the allocator collapses into
//    scratch (r1: 530MB, r6: 900MB of spill traffic) instead of landing at it.
//  - Instead diet the persistent state so the NATURAL allocation falls in the
//    5-waves/SIMD tier (<=102): wa3(16)+wa4(32) VGPRs -> LDS (r4-proven
//    neutral), b1/b3/b4 (36) -> LDS (C-operands, off the critical path).
//  - Keep the software prefetch rotation (r7 dropped it and regressed 83->104).
__global__ __launch_bounds__(256) void nerf_fused(
    const float* __restrict__ pos, const float* __restrict__ dir,
    const float* __restrict__ W1, const float* __restrict__ b1,
    const float* __restrict__ W2, const float* __restrict__ b2,
    const float* __restrict__ W3, const float* __restrict__ b3,
    const float* __restrict__ W4, const float* __restrict__ b4,
    const float* __restrict__ W5, const float* __restrict__ b5,
    float* __restrict__ outD, float* __restrict__ outC)
{
    // wa3 (4 combos) + wa4 (8 combos) A-fragments, lane-contiguous 16B rows
    // => conflict-free ds_read_b128. b1/b3/b4 linear; per-q f32x4 broadcasts.
    __shared__ s8    w3lds[4 * 64];
    __shared__ s8    w4lds[8 * 64];
    __shared__ float blds[3 * 64];

    const int tid  = threadIdx.x;
    const int w    = tid >> 6;
    const int lane = tid & 63;
    const int q    = lane >> 4;    // lane-group 0..3
    const int n    = lane & 15;    // A row / B col / sample-within-tile

    // ---------- LDS staging: wave w stages w3 combo w, w4 combos 2w,2w+1 ----------
    {
        s8 tmp;
        #pragma unroll
        for (int h = 0; h < 2; ++h)
            #pragma unroll
            for (int i = 0; i < 4; ++i)
                tmp[4*h+i] = bfs(W3[(16*h + 4*q + i) * 64 + 16*w + n]);         // [32,64]
        w3lds[w * 64 + lane] = tmp;
        #pragma unroll
        for (int cc = 0; cc < 2; ++cc) {
            s8 t4;
            #pragma unroll
            for (int h = 0; h < 2; ++h)
                #pragma unroll
                for (int i = 0; i < 4; ++i)
                    t4[4*h+i] = bfs(W4[(16*(2*cc+h) + 4*q + i) * 64 + 16*w + n]); // [64,64]
            w4lds[(2*w + cc) * 64 + lane] = t4;
        }
    }
    if (tid < 64) {
        blds[tid]       = b1[tid];
        blds[64 + tid]  = b3[tid];
        blds[128 + tid] = b4[tid];
    }
    __syncthreads();   // LDS read-only below

    // ---------- VGPR-resident weight A-fragments (small/hot layers) ----------
    s8 wa1[4], wa2x[2], wa5x[2];
    #pragma unroll
    for (int t = 0; t < 4; ++t)
        #pragma unroll
        for (int h = 0; h < 2; ++h)
            #pragma unroll
            for (int i = 0; i < 4; ++i)
                wa1[t][4*h+i] = bfs(W1[(16*h + 4*q + i) * 64 + 16*t + n]);      // [32,64]
    #pragma unroll
    for (int j = 0; j < 2; ++j)
        #pragma unroll
        for (int h = 0; h < 2; ++h)
            #pragma unroll
            for (int i = 0; i < 4; ++i)
                wa2x[j][4*h+i] = bfs(W2[(16*(2*j+h) + 4*q + i) * 16 + n]);      // [64,16]
    #pragma unroll
    for (int j = 0; j < 2; ++j)
        #pragma unroll
        for (int h = 0; h < 2; ++h)
            #pragma unroll
            for (int i = 0; i < 4; ++i)
                wa5x[j][4*h+i] = (n < 3) ? bfs(W5[(16*(2*j+h) + 4*q + i) * 3 + n])
                                         : (short)0;                             // [64,3] pad

    // small biases kept in regs
    f32x4 bi2, bi5;
    #pragma unroll
    for (int r = 0; r < 4; ++r) {
        bi2[r] = b2[4*q + r];
        bi5[r] = (q == 0 && r < 3) ? b5[r] : 0.f;
    }

    const int waveRow0 = blockIdx.x * ROWS_PER_BLOCK + w * (TPW * 16);

    // per-lane streaming pointers (constant per-tile strides)
    const float* pp = pos  + (size_t)(waveRow0 + n) * 32 + 4*q;
    const float* dp = dir  + (size_t)(waveRow0 + n) * 3;
    float*       pD = outD + (size_t)(waveRow0 + n) * 16 + 4*q;
    float*       pC = outC + (size_t)(waveRow0 + n) * 3;   // only used by q==0 lanes

    // prefetched raw inputs for tile 0
    f32x4 pa = *(const f32x4*)pp;
    f32x4 pb = *(const f32x4*)(pp + 16);
    float dx = dp[0], dy = dp[1], dz = dp[2];

    for (int t = 0; t < TPW; ++t) {
        // prefetch next tile's inputs (hide load latency under this tile's MFMAs)
        const float* ppn = pp + ((t + 1 < TPW) ? 16 * 32 : 0);
        const float* dpn = dp + ((t + 1 < TPW) ? 16 * 3  : 0);
        f32x4 pa2 = *(const f32x4*)ppn;
        f32x4 pb2 = *(const f32x4*)(ppn + 16);
        float dx2 = dpn[0], dy2 = dpn[1], dz2 = dpn[2];

        s8 xb = cat(pack4(pa), pack4(pb));

        // ---- L1: H^T = W1^T · X^T  (4 h-tiles, K=32) ----
        s4 hf[4];
        #pragma unroll
        for (int tt = 0; tt < 4; ++tt) {
            f32x4 bi = *(const f32x4*)(blds + 16*tt + 4*q);
            f32x4 h  = MFMA32(wa1[tt], xb, bi);
            hf[tt] = relu_pack4(h);          // D regs == next-layer B regs
        }

        // ---- L2: density (K=64 -> 2 chained MFMAs, no relu) ----
        f32x4 d2 = MFMA32(wa2x[0], cat(hf[0], hf[1]), bi2);
        d2 = MFMA32(wa2x[1], cat(hf[2], hf[3]), d2);

        // direct coalesced density store (lane(q,n): channels 4q..4q+3 of sample n)
        *(f32x4*)pD = d2;

        // ---- SH encoding (exec-masked by q; cost = sum of branches) ----
        f32x4 shv;
        {
            const float xx = dx*dx, yy = dy*dy, zz = dz*dz;
            if (q == 0) {
                shv[0] = 0.28209479177387814f;
                shv[1] = 0.4886025119029199f * dy;
                shv[2] = 0.4886025119029199f * dz;
                shv[3] = 0.4886025119029199f * dx;
            } else if (q == 1) {
                shv[0] = 1.0925484305920792f * dx * dy;
                shv[1] = 1.0925484305920792f * dy * dz;
                shv[2] = 0.9461746957575601f * zz - 0.31539156525252f;
                shv[3] = 1.0925484305920792f * dx * dz;
            } else if (q == 2) {
                shv[0] = 0.5462742152960396f * (xx - yy);
                shv[1] = 0.5900435899266435f * dy * (3.f*xx - yy);
                shv[2] = 2.890611442640554f * dx * dy * dz;
                shv[3] = 0.4570457994644658f * dy * (5.f*zz - 1.f);
            } else {
                shv[0] = 0.3731763325901154f * dz * (5.f*zz - 3.f);
                shv[1] = 0.4570457994644658f * dx * (5.f*zz - 1.f);
                shv[2] = 1.445305721320277f  * dz * (xx - yy);
                shv[3] = 0.5900435899266435f * dx * (xx - 3.f*yy);
            }
        }
        s8 cf = cat(pack4(d2), pack4(shv));

        // ---- L3: relu(W3^T · concat^T)  (weights from LDS, conflict-free) ----
        s4 gf[4];
        #pragma unroll
        for (int tt = 0; tt < 4; ++tt) {
            f32x4 bi = *(const f32x4*)(blds + 64 + 16*tt + 4*q);
            f32x4 g  = MFMA32(w3lds[tt * 64 + lane], cf, bi);
            gf[tt] = relu_pack4(g);
        }

        // ---- L4: relu(W4^T · H3^T)  (LDS weights, K=64 -> 2 chained MFMAs) ----
        s8 gl = cat(gf[0], gf[1]), gh = cat(gf[2], gf[3]);
        s4 ef[4];
        #pragma unroll
        for (int tt = 0; tt < 4; ++tt) {
            f32x4 bi = *(const f32x4*)(blds + 128 + 16*tt + 4*q);
            f32x4 e  = MFMA32(w4lds[(2*tt + 0) * 64 + lane], gl, bi);
            e = MFMA32(w4lds[(2*tt + 1) * 64 + lane], gh, e);
            ef[tt] = relu_pack4(e);
        }

        // ---- L5: color (K=64 -> 2 chained MFMAs) + sigmoid ----
        f32x4 c5 = MFMA32(wa5x[0], cat(ef[0], ef[1]), bi5);
        c5 = MFMA32(wa5x[1], cat(ef[2], ef[3]), c5);

        f32x4 cv;
        cv[0] = 1.f / (1.f + __expf(-c5[0]));
        cv[1] = 1.f / (1.f + __expf(-c5[1]));
        cv[2] = 1.f / (1.f + __expf(-c5[2]));
        if (q == 0) {
            pC[0] = cv[0];
            pC[1] = cv[1];
            pC[2] = cv[2];
        }

        pp += 16 * 32; dp += 16 * 3; pD += 16 * 16; pC += 16 * 3;
        pa = pa2; pb = pb2; dx = dx2; dy = dy2; dz = dz2;
    }
}

extern "C" void kernel_launch(void* const* d_in, const int* in_sizes, int n_in,
                              void* d_out, int out_size, void* d_ws, size_t ws_size,
                              hipStream_t stream) {
    const float* pos = (const float*)d_in[0];
    const float* dir = (const float*)d_in[1];
    const float* W1  = (const float*)d_in[2];
    const float* b1  = (const float*)d_in[3];
    const float* W2  = (const float*)d_in[4];
    const float* b2  = (const float*)d_in[5];
    const float* W3  = (const float*)d_in[6];
    const float* b3  = (const float*)d_in[7];
    const float* W4  = (const float*)d_in[8];
    const float* b4  = (const float*)d_in[9];
    const float* W5  = (const float*)d_in[10];
    const float* b5  = (const float*)d_in[11];

    const int N = in_sizes[0] / 32;           // 1<<20
    float* outD = (float*)d_out;              // [N,16]
    float* outC = outD + (size_t)N * 16;      // [N,3]

    const int grid = N / ROWS_PER_BLOCK;      // 2048
    nerf_fused<<<grid, WAVES * 64, 0, stream>>>(pos, dir, W1, b1, W2, b2, W3, b3,
                                                W4, b4, W5, b5, outD, outC);
}